// Round 1
// baseline (2545.148 us; speedup 1.0000x reference)
//
#include <hip/hip_runtime.h>
#include <math.h>

#define NH 16
#define HD 64
#define HID 1024
#define SEQ 2048
#define NB 2

constexpr float LN_EPS_C = 1e-5f;
constexpr float SM_SCALE = 0.07216878364870323f; // 1/sqrt(64*3)

// ---------------- LayerNorm over relpos_table rows ----------------
__global__ __launch_bounds__(256) void ln_kernel(const float* __restrict__ tbl,
    const float* __restrict__ gamma, const float* __restrict__ beta,
    float* __restrict__ e) {
  int row = blockIdx.x;
  int t = threadIdx.x;
  const float4* rp = reinterpret_cast<const float4*>(tbl + (size_t)row * HID);
  float4 x = rp[t];
  float s = x.x + x.y + x.z + x.w;
  float ss = x.x * x.x + x.y * x.y + x.z * x.z + x.w * x.w;
  #pragma unroll
  for (int o = 1; o < 64; o <<= 1) {
    s += __shfl_xor(s, o);
    ss += __shfl_xor(ss, o);
  }
  __shared__ float sb[4], ssb[4];
  int w = t >> 6;
  if ((t & 63) == 0) { sb[w] = s; ssb[w] = ss; }
  __syncthreads();
  s = sb[0] + sb[1] + sb[2] + sb[3];
  ss = ssb[0] + ssb[1] + ssb[2] + ssb[3];
  float mu = s * (1.0f / HID);
  float var = ss * (1.0f / HID) - mu * mu;
  float rs = rsqrtf(var + LN_EPS_C);
  float4 g = reinterpret_cast<const float4*>(gamma)[t];
  float4 bt = reinterpret_cast<const float4*>(beta)[t];
  float4 o4;
  o4.x = (x.x - mu) * rs * g.x + bt.x;
  o4.y = (x.y - mu) * rs * g.y + bt.y;
  o4.z = (x.z - mu) * rs * g.z + bt.z;
  o4.w = (x.w - mu) * rs * g.w + bt.w;
  reinterpret_cast<float4*>(e + (size_t)row * HID)[t] = o4;
}

// ---------------- Tiled f32 GEMM: C[M x 1024] = A[M x 1024] @ W[1024 x 1024] + bias ----------------
__global__ __launch_bounds__(256) void gemm64(const float* __restrict__ A,
    const float* __restrict__ W, const float* __restrict__ bias,
    float* __restrict__ C) {
  __shared__ float As[16][68]; // As[k][m]
  __shared__ float Ws[16][68]; // Ws[k][n]
  int t = threadIdx.x;
  int cb = blockIdx.x * 64;
  int rb = blockIdx.y * 64;
  int tx = t & 15, ty = t >> 4;
  int ar = t >> 2, ac = (t & 3) << 2;
  int wr = t >> 4, wc = (t & 15) << 2;
  float acc[4][4] = {};
  const float* Aptr = A + (size_t)(rb + ar) * HID + ac;
  const float* Wptr = W + (size_t)wr * HID + cb + wc;
  for (int kk = 0; kk < HID; kk += 16) {
    float4 av = *reinterpret_cast<const float4*>(Aptr + kk);
    float4 wv = *reinterpret_cast<const float4*>(Wptr + (size_t)kk * HID);
    __syncthreads();
    As[ac + 0][ar] = av.x;
    As[ac + 1][ar] = av.y;
    As[ac + 2][ar] = av.z;
    As[ac + 3][ar] = av.w;
    *reinterpret_cast<float4*>(&Ws[wr][wc]) = wv;
    __syncthreads();
    #pragma unroll
    for (int k = 0; k < 16; ++k) {
      float4 a = *reinterpret_cast<const float4*>(&As[k][ty << 2]);
      float4 b = *reinterpret_cast<const float4*>(&Ws[k][tx << 2]);
      acc[0][0] += a.x * b.x; acc[0][1] += a.x * b.y; acc[0][2] += a.x * b.z; acc[0][3] += a.x * b.w;
      acc[1][0] += a.y * b.x; acc[1][1] += a.y * b.y; acc[1][2] += a.y * b.z; acc[1][3] += a.y * b.w;
      acc[2][0] += a.z * b.x; acc[2][1] += a.z * b.y; acc[2][2] += a.z * b.z; acc[2][3] += a.z * b.w;
      acc[3][0] += a.w * b.x; acc[3][1] += a.w * b.y; acc[3][2] += a.w * b.z; acc[3][3] += a.w * b.w;
    }
  }
  float4 bv = *reinterpret_cast<const float4*>(bias + cb + (tx << 2));
  #pragma unroll
  for (int i = 0; i < 4; ++i) {
    float4 o4;
    o4.x = acc[i][0] + bv.x;
    o4.y = acc[i][1] + bv.y;
    o4.z = acc[i][2] + bv.z;
    o4.w = acc[i][3] + bv.w;
    *reinterpret_cast<float4*>(&C[(size_t)(rb + (ty << 2) + i) * HID + cb + (tx << 2)]) = o4;
  }
}

// ---------------- Fused causal attention with relative-position biases ----------------
// One block per (b, h, 32-row q-tile). Iterates 32-col k-tiles with online softmax.
// S[q][k] = (q.k + q.rk[rel] + k.rq[rel]) * SM_SCALE, rel = max(511-(q-k), 0)
__global__ __launch_bounds__(256) void attn_kernel(const float* __restrict__ Qm,
    const float* __restrict__ Km, const float* __restrict__ Vm,
    const float* __restrict__ RKm, const float* __restrict__ RQm,
    float* __restrict__ ATT) {
  int qt = (gridDim.x - 1) - blockIdx.x; // heaviest tiles scheduled first
  int h = blockIdx.y;
  int b = blockIdx.z;
  int q0 = qt * 32;
  int t = threadIdx.x;

  __shared__ float QsT[64][33];  // QsT[d][q]
  __shared__ float KsT[64][33];  // KsT[d][k]
  __shared__ float Vs[32][68];   // Vs[k][d]
  __shared__ float RKsT[64][63]; // RKsT[d][idx], idx = (q-k) - dbase in [0,62]
  __shared__ float RQsT[64][63];
  __shared__ float Ss[32][33];

  // load Q tile (transposed)
  for (int e2 = t; e2 < 512; e2 += 256) {
    int r = e2 >> 4, c = (e2 & 15) << 2;
    float4 qv = *reinterpret_cast<const float4*>(&Qm[(size_t)(b * SEQ + q0 + r) * HID + h * HD + c]);
    QsT[c + 0][r] = qv.x; QsT[c + 1][r] = qv.y; QsT[c + 2][r] = qv.z; QsT[c + 3][r] = qv.w;
  }

  int q2 = t >> 4, k2 = t & 15;   // S-compute mapping: 2x2 block per thread
  int qr = t >> 3, g = t & 7, d0 = g << 3; // softmax/PV mapping
  float m = -INFINITY, l = 0.0f;
  float o[8] = {};

  for (int kt = 0; kt <= qt; ++kt) {
    int k0 = kt * 32;
    int dbase = q0 - k0 - 31;
    __syncthreads(); // previous iteration's PV done before overwriting tiles
    for (int e2 = t; e2 < 512; e2 += 256) {
      int r = e2 >> 4, c = (e2 & 15) << 2;
      size_t base = (size_t)(b * SEQ + k0 + r) * HID + h * HD + c;
      float4 kv = *reinterpret_cast<const float4*>(&Km[base]);
      KsT[c + 0][r] = kv.x; KsT[c + 1][r] = kv.y; KsT[c + 2][r] = kv.z; KsT[c + 3][r] = kv.w;
      float4 vv = *reinterpret_cast<const float4*>(&Vm[base]);
      *reinterpret_cast<float4*>(&Vs[r][c]) = vv;
    }
    for (int e2 = t; e2 < 63 * 16; e2 += 256) {
      int r = e2 >> 4, c = (e2 & 15) << 2;
      int d = dbase + r;
      int w = 511 - d;
      w = (w < 0) ? 0 : (w > 511 ? 511 : w); // d>511 -> row 0; d<0 entries are masked anyway
      float4 rkv = *reinterpret_cast<const float4*>(&RKm[(size_t)w * HID + h * HD + c]);
      RKsT[c + 0][r] = rkv.x; RKsT[c + 1][r] = rkv.y; RKsT[c + 2][r] = rkv.z; RKsT[c + 3][r] = rkv.w;
      float4 rqv = *reinterpret_cast<const float4*>(&RQm[(size_t)w * HID + h * HD + c]);
      RQsT[c + 0][r] = rqv.x; RQsT[c + 1][r] = rqv.y; RQsT[c + 2][r] = rqv.z; RQsT[c + 3][r] = rqv.w;
    }
    __syncthreads();
    // ---- logits for 2x2 block ----
    float a00 = 0.f, a01 = 0.f, a10 = 0.f, a11 = 0.f;
    int ib = 2 * (q2 - k2) + 31; // idx for (dq,dk)=(0,0)/(1,1); (0,1)->ib-1; (1,0)->ib+1
    #pragma unroll 8
    for (int i = 0; i < 64; ++i) {
      float qa = QsT[i][2 * q2], qb = QsT[i][2 * q2 + 1];
      float ka = KsT[i][2 * k2], kb = KsT[i][2 * k2 + 1];
      float r0 = RKsT[i][ib], rm = RKsT[i][ib - 1], rp = RKsT[i][ib + 1];
      float u0 = RQsT[i][ib], um = RQsT[i][ib - 1], up = RQsT[i][ib + 1];
      a00 += qa * (ka + r0) + ka * u0;
      a01 += qa * (kb + rm) + kb * um;
      a10 += qb * (ka + rp) + ka * up;
      a11 += qb * (kb + r0) + kb * u0;
    }
    int gq = q0 + 2 * q2, gk = k0 + 2 * k2;
    Ss[2 * q2][2 * k2]         = (gq     >= gk    ) ? a00 * SM_SCALE : -INFINITY;
    Ss[2 * q2][2 * k2 + 1]     = (gq     >= gk + 1) ? a01 * SM_SCALE : -INFINITY;
    Ss[2 * q2 + 1][2 * k2]     = (gq + 1 >= gk    ) ? a10 * SM_SCALE : -INFINITY;
    Ss[2 * q2 + 1][2 * k2 + 1] = (gq + 1 >= gk + 1) ? a11 * SM_SCALE : -INFINITY;
    __syncthreads();
    // ---- online softmax (8 threads per q-row) ----
    float s0 = Ss[qr][(g << 2) + 0], s1 = Ss[qr][(g << 2) + 1],
          s2 = Ss[qr][(g << 2) + 2], s3 = Ss[qr][(g << 2) + 3];
    float mx = fmaxf(fmaxf(s0, s1), fmaxf(s2, s3));
    mx = fmaxf(mx, __shfl_xor(mx, 1));
    mx = fmaxf(mx, __shfl_xor(mx, 2));
    mx = fmaxf(mx, __shfl_xor(mx, 4));
    float mnew = fmaxf(m, mx);
    float alpha = __expf(m - mnew); // m=-inf on first tile -> alpha=0
    float p0 = __expf(s0 - mnew), p1 = __expf(s1 - mnew),
          p2 = __expf(s2 - mnew), p3 = __expf(s3 - mnew);
    float ps = p0 + p1 + p2 + p3;
    ps += __shfl_xor(ps, 1);
    ps += __shfl_xor(ps, 2);
    ps += __shfl_xor(ps, 4);
    l = l * alpha + ps;
    m = mnew;
    Ss[qr][(g << 2) + 0] = p0;
    Ss[qr][(g << 2) + 1] = p1;
    Ss[qr][(g << 2) + 2] = p2;
    Ss[qr][(g << 2) + 3] = p3;
    __syncthreads();
    // ---- PV accumulate: thread owns (q-row, 8 dims) ----
    #pragma unroll
    for (int j = 0; j < 8; ++j) o[j] *= alpha;
    #pragma unroll 4
    for (int k = 0; k < 32; ++k) {
      float p = Ss[qr][k];
      float4 v0 = *reinterpret_cast<const float4*>(&Vs[k][d0]);
      float4 v1 = *reinterpret_cast<const float4*>(&Vs[k][d0 + 4]);
      o[0] += p * v0.x; o[1] += p * v0.y; o[2] += p * v0.z; o[3] += p * v0.w;
      o[4] += p * v1.x; o[5] += p * v1.y; o[6] += p * v1.z; o[7] += p * v1.w;
    }
  }
  float inv = 1.0f / l;
  float4 o0, o1;
  o0.x = o[0] * inv; o0.y = o[1] * inv; o0.z = o[2] * inv; o0.w = o[3] * inv;
  o1.x = o[4] * inv; o1.y = o[5] * inv; o1.z = o[6] * inv; o1.w = o[7] * inv;
  size_t ob = (size_t)(b * SEQ + q0 + qr) * HID + h * HD + d0;
  *reinterpret_cast<float4*>(&ATT[ob]) = o0;
  *reinterpret_cast<float4*>(&ATT[ob + 4]) = o1;
}

extern "C" void kernel_launch(void* const* d_in, const int* in_sizes, int n_in,
                              void* d_out, int out_size, void* d_ws, size_t ws_size,
                              hipStream_t stream) {
  const float* x      = (const float*)d_in[0];
  const float* Wq     = (const float*)d_in[1];
  const float* bq     = (const float*)d_in[2];
  const float* Wk     = (const float*)d_in[3];
  const float* bk     = (const float*)d_in[4];
  const float* Wv     = (const float*)d_in[5];
  const float* bv     = (const float*)d_in[6];
  const float* Wo     = (const float*)d_in[7];
  const float* bo     = (const float*)d_in[8];
  const float* relpos = (const float*)d_in[9];
  const float* gamma  = (const float*)d_in[10];
  const float* beta   = (const float*)d_in[11];
  const float* Wrk    = (const float*)d_in[12];
  const float* brk    = (const float*)d_in[13];
  const float* Wrq    = (const float*)d_in[14];
  const float* brq    = (const float*)d_in[15];
  float* out = (float*)d_out;
  float* ws  = (float*)d_ws;

  float* Q   = ws;                    // 4096x1024
  float* Kp  = ws + 4194304;          // 4096x1024
  float* Vp  = ws + 8388608;          // 4096x1024
  float* ATT = ws + 12582912;         // 4096x1024
  float* E   = ws + 16777216;         // 512x1024
  float* RK  = ws + 17301504;         // 512x1024
  float* RQ  = ws + 17825792;         // 512x1024

  ln_kernel<<<512, 256, 0, stream>>>(relpos, gamma, beta, E);

  dim3 gBig(16, 64);
  gemm64<<<gBig, 256, 0, stream>>>(x, Wq, bq, Q);
  gemm64<<<gBig, 256, 0, stream>>>(x, Wk, bk, Kp);
  gemm64<<<gBig, 256, 0, stream>>>(x, Wv, bv, Vp);
  dim3 gRel(16, 8);
  gemm64<<<gRel, 256, 0, stream>>>(E, Wrk, brk, RK);
  gemm64<<<gRel, 256, 0, stream>>>(E, Wrq, brq, RQ);

  dim3 gAtt(64, NH, NB);
  attn_kernel<<<gAtt, 256, 0, stream>>>(Q, Kp, Vp, RK, RQ, ATT);

  gemm64<<<gBig, 256, 0, stream>>>(ATT, Wo, bo, out);
}

// Round 2
// 418.257 us; speedup vs baseline: 6.0851x; 6.0851x over previous
//
#include <hip/hip_runtime.h>
#include <math.h>

#define NH 16
#define HD 64
#define HID 1024
#define SEQ 2048
#define NB 2

typedef __attribute__((ext_vector_type(8))) short short8;
typedef __attribute__((ext_vector_type(4))) float f32x4;

constexpr float LN_EPS_C = 1e-5f;
constexpr float SM_SCALE = 0.07216878364870323f; // 1/sqrt(64*3)

__device__ inline unsigned short f2b(float f) {
  unsigned u = __builtin_bit_cast(unsigned, f);
  u = (u + 0x7FFFu + ((u >> 16) & 1u)) >> 16;
  return (unsigned short)u;
}
__device__ inline float b2f(unsigned short h) {
  unsigned u = ((unsigned)h) << 16;
  return __builtin_bit_cast(float, u);
}
__device__ inline f32x4 mfma16(short8 a, short8 b, f32x4 c) {
  return __builtin_amdgcn_mfma_f32_16x16x32_bf16(a, b, c, 0, 0, 0);
}

// ---------------- LayerNorm over relpos_table rows -> bf16 ----------------
__global__ __launch_bounds__(256) void ln_kernel(const float* __restrict__ tbl,
    const float* __restrict__ gamma, const float* __restrict__ beta,
    unsigned short* __restrict__ e) {
  int row = blockIdx.x;
  int t = threadIdx.x;
  const float4* rp = reinterpret_cast<const float4*>(tbl + (size_t)row * HID);
  float4 x = rp[t];
  float s = x.x + x.y + x.z + x.w;
  float ss = x.x * x.x + x.y * x.y + x.z * x.z + x.w * x.w;
  #pragma unroll
  for (int o = 1; o < 64; o <<= 1) {
    s += __shfl_xor(s, o);
    ss += __shfl_xor(ss, o);
  }
  __shared__ float sb[4], ssb[4];
  int w = t >> 6;
  if ((t & 63) == 0) { sb[w] = s; ssb[w] = ss; }
  __syncthreads();
  s = sb[0] + sb[1] + sb[2] + sb[3];
  ss = ssb[0] + ssb[1] + ssb[2] + ssb[3];
  float mu = s * (1.0f / HID);
  float var = ss * (1.0f / HID) - mu * mu;
  float rs = rsqrtf(var + LN_EPS_C);
  float4 g = reinterpret_cast<const float4*>(gamma)[t];
  float4 bt = reinterpret_cast<const float4*>(beta)[t];
  ushort4 o4;
  o4.x = f2b((x.x - mu) * rs * g.x + bt.x);
  o4.y = f2b((x.y - mu) * rs * g.y + bt.y);
  o4.z = f2b((x.z - mu) * rs * g.z + bt.z);
  o4.w = f2b((x.w - mu) * rs * g.w + bt.w);
  *reinterpret_cast<ushort4*>(&e[(size_t)row * HID + t * 4]) = o4;
}

// ---------------- f32 -> bf16 convert ----------------
__global__ __launch_bounds__(256) void conv_bf16(const float* __restrict__ src,
    unsigned short* __restrict__ dst, int n) {
  int i = (blockIdx.x * 256 + threadIdx.x) * 8;
  if (i >= n) return;
  float4 a = *reinterpret_cast<const float4*>(&src[i]);
  float4 c = *reinterpret_cast<const float4*>(&src[i + 4]);
  short8 o;
  o[0] = (short)f2b(a.x); o[1] = (short)f2b(a.y); o[2] = (short)f2b(a.z); o[3] = (short)f2b(a.w);
  o[4] = (short)f2b(c.x); o[5] = (short)f2b(c.y); o[6] = (short)f2b(c.z); o[7] = (short)f2b(c.w);
  *reinterpret_cast<short8*>(&dst[i]) = o;
}

// ---------------- W[k][n] f32 -> Wt[n][k] bf16 (transpose+convert) ----------------
__global__ __launch_bounds__(256) void transp_w(const float* __restrict__ W,
    unsigned short* __restrict__ Wt) {
  __shared__ float T[32][33];
  int bn = blockIdx.x * 32, bk = blockIdx.y * 32;
  int t = threadIdx.x;
  int r = t >> 3, c4 = (t & 7) * 4;
  float4 v = *reinterpret_cast<const float4*>(&W[(size_t)(bk + r) * HID + bn + c4]);
  T[r][c4 + 0] = v.x; T[r][c4 + 1] = v.y; T[r][c4 + 2] = v.z; T[r][c4 + 3] = v.w;
  __syncthreads();
  int n = t >> 3, k4 = (t & 7) * 4;
  ushort4 o;
  o.x = f2b(T[k4 + 0][n]); o.y = f2b(T[k4 + 1][n]);
  o.z = f2b(T[k4 + 2][n]); o.w = f2b(T[k4 + 3][n]);
  *reinterpret_cast<ushort4*>(&Wt[(size_t)(bn + n) * HID + bk + k4]) = o;
}

// ---------------- bf16 MFMA GEMM: C[M x1024] = A @ W (+bias), Bt[n][k] ----------------
template <bool F32OUT>
__global__ __launch_bounds__(256) void gemm_bf16(const unsigned short* __restrict__ A,
    const unsigned short* __restrict__ Bt, const float* __restrict__ bias,
    void* __restrict__ Cout) {
  __shared__ unsigned short Al[128 * 40];
  __shared__ unsigned short Bl[128 * 40];
  int t = threadIdx.x;
  int cb = blockIdx.x * 128, rb = blockIdx.y * 128;
  int wv = t >> 6, lane = t & 63, l15 = lane & 15, lg = lane >> 4;
  int wr = (wv >> 1) * 64, wc = (wv & 1) * 64;
  f32x4 acc[4][4];
  #pragma unroll
  for (int i = 0; i < 4; ++i)
    #pragma unroll
    for (int j = 0; j < 4; ++j) acc[i][j] = (f32x4){0.f, 0.f, 0.f, 0.f};
  int sr = t >> 1, sc = (t & 1) * 8;
  const unsigned short* Ap = A + (size_t)(rb + sr) * HID;
  const unsigned short* Bp = Bt + (size_t)(cb + sr) * HID;
  for (int kk = 0; kk < HID; kk += 32) {
    __syncthreads();
    *reinterpret_cast<short8*>(&Al[sr * 40 + sc]) = *reinterpret_cast<const short8*>(&Ap[kk + sc]);
    *reinterpret_cast<short8*>(&Al[sr * 40 + sc + 16]) = *reinterpret_cast<const short8*>(&Ap[kk + sc + 16]);
    *reinterpret_cast<short8*>(&Bl[sr * 40 + sc]) = *reinterpret_cast<const short8*>(&Bp[kk + sc]);
    *reinterpret_cast<short8*>(&Bl[sr * 40 + sc + 16]) = *reinterpret_cast<const short8*>(&Bp[kk + sc + 16]);
    __syncthreads();
    short8 am[4], bn[4];
    #pragma unroll
    for (int i = 0; i < 4; ++i)
      am[i] = *reinterpret_cast<const short8*>(&Al[(wr + i * 16 + l15) * 40 + lg * 8]);
    #pragma unroll
    for (int j = 0; j < 4; ++j)
      bn[j] = *reinterpret_cast<const short8*>(&Bl[(wc + j * 16 + l15) * 40 + lg * 8]);
    #pragma unroll
    for (int i = 0; i < 4; ++i)
      #pragma unroll
      for (int j = 0; j < 4; ++j)
        acc[i][j] = mfma16(am[i], bn[j], acc[i][j]);
  }
  #pragma unroll
  for (int j = 0; j < 4; ++j) {
    float bv = bias[cb + wc + j * 16 + l15];
    #pragma unroll
    for (int i = 0; i < 4; ++i) {
      #pragma unroll
      for (int r = 0; r < 4; ++r) {
        size_t idx = (size_t)(rb + wr + i * 16 + lg * 4 + r) * HID + cb + wc + j * 16 + l15;
        float v = acc[i][j][r] + bv;
        if (F32OUT) reinterpret_cast<float*>(Cout)[idx] = v;
        else reinterpret_cast<unsigned short*>(Cout)[idx] = f2b(v);
      }
    }
  }
}

// ---------------- rank-1 bias precompute: qrk0 = Q.rk[0], krq0 = K.rq[0] ----------------
__global__ __launch_bounds__(256) void biasqk(const unsigned short* __restrict__ Qb,
    const unsigned short* __restrict__ Kb, const unsigned short* __restrict__ RKb,
    const unsigned short* __restrict__ RQb, float* __restrict__ qrk0,
    float* __restrict__ krq0) {
  int o = blockIdx.x * 64 + (threadIdx.x >> 2);
  int sub = threadIdx.x & 3;
  int b = o >> 15, h = (o >> 11) & 15, i = o & 2047;
  size_t rbase = (size_t)(b * SEQ + i) * HID + h * HD + sub * 16;
  size_t tbase = (size_t)h * HD + sub * 16;
  float s1 = 0.f, s2 = 0.f;
  #pragma unroll
  for (int c = 0; c < 2; ++c) {
    short8 qv = *reinterpret_cast<const short8*>(&Qb[rbase + c * 8]);
    short8 rv = *reinterpret_cast<const short8*>(&RKb[tbase + c * 8]);
    short8 kv = *reinterpret_cast<const short8*>(&Kb[rbase + c * 8]);
    short8 uv = *reinterpret_cast<const short8*>(&RQb[tbase + c * 8]);
    #pragma unroll
    for (int j = 0; j < 8; ++j) {
      s1 += b2f((unsigned short)qv[j]) * b2f((unsigned short)rv[j]);
      s2 += b2f((unsigned short)kv[j]) * b2f((unsigned short)uv[j]);
    }
  }
  s1 += __shfl_xor(s1, 1); s1 += __shfl_xor(s1, 2);
  s2 += __shfl_xor(s2, 1); s2 += __shfl_xor(s2, 2);
  if (sub == 0) { qrk0[o] = s1; krq0[o] = s2; }
}

// ---------------- fused DeBERTa attention, MFMA flash, 64x64 tiles ----------------
// dt = qt-kt >= 9  -> rank-1 bias (q.rk0 + k.rq0); dt <= 8 -> banded: G1=Q.RKband^T,
// G2=K.RQband^T via MFMA, gathered per element (w = max(511-(q-k),0)).
__global__ __launch_bounds__(256) void attn_mfma(
    const unsigned short* __restrict__ Qb, const unsigned short* __restrict__ Kb,
    const unsigned short* __restrict__ Vb, const unsigned short* __restrict__ RKb,
    const unsigned short* __restrict__ RQb, const float* __restrict__ qrk0,
    const float* __restrict__ krq0, unsigned short* __restrict__ ATT) {
  __shared__ unsigned short smem[32256];
  unsigned short* Ks = smem;          // [64][72]  K[k][d]
  unsigned short* Vt = smem + 4608;   // [64][72]  V^T[d][k]
  unsigned short* Ps = smem + 9216;   // [64][72]  P[q][k]
  unsigned short* U  = smem + 13824;  // 18432 ushorts, union:
  unsigned short* RKB = U;            //   [128][72] band rk
  unsigned short* RQB = U + 9216;     //   [128][72] band rq
  unsigned short* G1  = U;            //   [64][132] q x w
  unsigned short* G2  = U + 8448;     //   [64][132] k x w

  int qt = (int)gridDim.x - 1 - (int)blockIdx.x; // heavy tiles first
  int h = blockIdx.y, b = blockIdx.z;
  int q0 = qt * 64;
  int t = threadIdx.x;
  int wv = t >> 6, lane = t & 63, l15 = lane & 15, lg = lane >> 4;
  int qs = q0 + wv * 16;
  int hoff = h * HD;
  int bh = (b * NH + h) * SEQ;

  size_t qgrow = (size_t)(b * SEQ + qs + l15) * HID + hoff;
  short8 aq0 = *reinterpret_cast<const short8*>(&Qb[qgrow + lg * 8]);
  short8 aq1 = *reinterpret_cast<const short8*>(&Qb[qgrow + 32 + lg * 8]);
  float qb0[4];
  #pragma unroll
  for (int r = 0; r < 4; ++r) qb0[r] = qrk0[bh + qs + lg * 4 + r];

  float m_[4], l_[4];
  f32x4 o[4];
  #pragma unroll
  for (int r = 0; r < 4; ++r) { m_[r] = -INFINITY; l_[r] = 0.f; }
  #pragma unroll
  for (int c = 0; c < 4; ++c) o[c] = (f32x4){0.f, 0.f, 0.f, 0.f};

  int sr = t >> 2, sc8 = (t & 3) * 8;

  for (int kt = 0; kt <= qt; ++kt) {
    int k0 = kt * 64;
    int dt = qt - kt;
    bool banded = (dt <= 8);
    int wlo = 448 - 64 * dt; if (wlo < 0) wlo = 0;
    __syncthreads();
    {
      const unsigned short* kg = &Kb[(size_t)(b * SEQ + k0 + sr) * HID + hoff];
      *reinterpret_cast<short8*>(&Ks[sr * 72 + sc8]) = *reinterpret_cast<const short8*>(&kg[sc8]);
      *reinterpret_cast<short8*>(&Ks[sr * 72 + sc8 + 32]) = *reinterpret_cast<const short8*>(&kg[sc8 + 32]);
      const unsigned short* vg = &Vb[(size_t)(b * SEQ + k0 + sr) * HID + hoff];
      short8 v0 = *reinterpret_cast<const short8*>(&vg[sc8]);
      short8 v1 = *reinterpret_cast<const short8*>(&vg[sc8 + 32]);
      #pragma unroll
      for (int j = 0; j < 8; ++j) Vt[(sc8 + j) * 72 + sr] = (unsigned short)v0[j];
      #pragma unroll
      for (int j = 0; j < 8; ++j) Vt[(sc8 + 32 + j) * 72 + sr] = (unsigned short)v1[j];
      if (banded) {
        for (int i = t; i < 1024; i += 256) {
          int rr = i >> 3, cc = (i & 7) * 8;
          int wr2 = wlo + rr; if (wr2 > 511) wr2 = 511;
          size_t gb = (size_t)wr2 * HID + hoff + cc;
          *reinterpret_cast<short8*>(&RKB[rr * 72 + cc]) = *reinterpret_cast<const short8*>(&RKb[gb]);
          *reinterpret_cast<short8*>(&RQB[rr * 72 + cc]) = *reinterpret_cast<const short8*>(&RQb[gb]);
        }
      }
    }
    float kq[4];
    if (!banded) {
      #pragma unroll
      for (int c = 0; c < 4; ++c) kq[c] = krq0[bh + k0 + c * 16 + l15];
    }
    __syncthreads();

    f32x4 s[4];
    #pragma unroll
    for (int c = 0; c < 4; ++c) s[c] = (f32x4){0.f, 0.f, 0.f, 0.f};

    if (banded) {
      f32x4 g1[8], g2[8];
      short8 ak0 = *reinterpret_cast<const short8*>(&Ks[(wv * 16 + l15) * 72 + lg * 8]);
      short8 ak1 = *reinterpret_cast<const short8*>(&Ks[(wv * 16 + l15) * 72 + 32 + lg * 8]);
      #pragma unroll
      for (int c = 0; c < 8; ++c) {
        f32x4 z = (f32x4){0.f, 0.f, 0.f, 0.f};
        short8 rb0 = *reinterpret_cast<const short8*>(&RKB[(c * 16 + l15) * 72 + lg * 8]);
        short8 rb1 = *reinterpret_cast<const short8*>(&RKB[(c * 16 + l15) * 72 + 32 + lg * 8]);
        g1[c] = mfma16(aq1, rb1, mfma16(aq0, rb0, z));
        short8 u0 = *reinterpret_cast<const short8*>(&RQB[(c * 16 + l15) * 72 + lg * 8]);
        short8 u1 = *reinterpret_cast<const short8*>(&RQB[(c * 16 + l15) * 72 + 32 + lg * 8]);
        g2[c] = mfma16(ak1, u1, mfma16(ak0, u0, z));
      }
      __syncthreads(); // all band reads complete before overwriting union with G
      #pragma unroll
      for (int c = 0; c < 8; ++c) {
        #pragma unroll
        for (int r = 0; r < 4; ++r) {
          G1[(wv * 16 + lg * 4 + r) * 132 + c * 16 + l15] = f2b(g1[c][r]);
          G2[(wv * 16 + lg * 4 + r) * 132 + c * 16 + l15] = f2b(g2[c][r]);
        }
      }
      #pragma unroll
      for (int c = 0; c < 4; ++c) { // c2c overlaps G-write latency
        short8 kb0 = *reinterpret_cast<const short8*>(&Ks[(c * 16 + l15) * 72 + lg * 8]);
        short8 kb1 = *reinterpret_cast<const short8*>(&Ks[(c * 16 + l15) * 72 + 32 + lg * 8]);
        s[c] = mfma16(aq1, kb1, mfma16(aq0, kb0, s[c]));
      }
      __syncthreads(); // G visible to all waves
      #pragma unroll
      for (int c = 0; c < 4; ++c) {
        #pragma unroll
        for (int r = 0; r < 4; ++r) {
          int q = qs + lg * 4 + r;
          int k = k0 + c * 16 + l15;
          int wi = 511 - (q - k) - wlo; if (wi < 0) wi = 0;
          s[c][r] += b2f(G1[(wv * 16 + lg * 4 + r) * 132 + wi]) +
                     b2f(G2[(c * 16 + l15) * 132 + wi]);
        }
      }
    } else {
      #pragma unroll
      for (int c = 0; c < 4; ++c) {
        short8 kb0 = *reinterpret_cast<const short8*>(&Ks[(c * 16 + l15) * 72 + lg * 8]);
        short8 kb1 = *reinterpret_cast<const short8*>(&Ks[(c * 16 + l15) * 72 + 32 + lg * 8]);
        s[c] = mfma16(aq1, kb1, mfma16(aq0, kb0, s[c]));
        #pragma unroll
        for (int r = 0; r < 4; ++r) s[c][r] += qb0[r] + kq[c];
      }
    }
    // scale + causal mask (only diagonal tiles need masking)
    #pragma unroll
    for (int c = 0; c < 4; ++c) {
      #pragma unroll
      for (int r = 0; r < 4; ++r) {
        float v = s[c][r] * SM_SCALE;
        if (dt == 0) {
          int ql = wv * 16 + lg * 4 + r, kl = c * 16 + l15;
          if (ql < kl) v = -INFINITY;
        }
        s[c][r] = v;
      }
    }
    // online softmax (per wave: 16 q-rows, row = lg*4+r across l15 lanes)
    float alpha[4];
    #pragma unroll
    for (int r = 0; r < 4; ++r) {
      float mx = fmaxf(fmaxf(s[0][r], s[1][r]), fmaxf(s[2][r], s[3][r]));
      mx = fmaxf(mx, __shfl_xor(mx, 1));
      mx = fmaxf(mx, __shfl_xor(mx, 2));
      mx = fmaxf(mx, __shfl_xor(mx, 4));
      mx = fmaxf(mx, __shfl_xor(mx, 8));
      float mn = fmaxf(m_[r], mx);
      alpha[r] = __expf(m_[r] - mn);
      float ps = 0.f;
      #pragma unroll
      for (int c = 0; c < 4; ++c) {
        float p = __expf(s[c][r] - mn);
        s[c][r] = p;
        ps += p;
      }
      ps += __shfl_xor(ps, 1);
      ps += __shfl_xor(ps, 2);
      ps += __shfl_xor(ps, 4);
      ps += __shfl_xor(ps, 8);
      l_[r] = l_[r] * alpha[r] + ps;
      m_[r] = mn;
    }
    // P -> LDS (wave-local region), rescale O
    #pragma unroll
    for (int c = 0; c < 4; ++c) {
      #pragma unroll
      for (int r = 0; r < 4; ++r) {
        Ps[(wv * 16 + lg * 4 + r) * 72 + c * 16 + l15] = f2b(s[c][r]);
        o[c][r] *= alpha[r];
      }
    }
    short8 ap0 = *reinterpret_cast<const short8*>(&Ps[(wv * 16 + l15) * 72 + lg * 8]);
    short8 ap1 = *reinterpret_cast<const short8*>(&Ps[(wv * 16 + l15) * 72 + 32 + lg * 8]);
    #pragma unroll
    for (int c = 0; c < 4; ++c) {
      short8 vb0 = *reinterpret_cast<const short8*>(&Vt[(c * 16 + l15) * 72 + lg * 8]);
      short8 vb1 = *reinterpret_cast<const short8*>(&Vt[(c * 16 + l15) * 72 + 32 + lg * 8]);
      o[c] = mfma16(ap1, vb1, mfma16(ap0, vb0, o[c]));
    }
  }
  #pragma unroll
  for (int r = 0; r < 4; ++r) l_[r] = 1.0f / l_[r];
  #pragma unroll
  for (int c = 0; c < 4; ++c) {
    #pragma unroll
    for (int r = 0; r < 4; ++r) {
      size_t ob = (size_t)(b * SEQ + qs + lg * 4 + r) * HID + hoff + c * 16 + l15;
      ATT[ob] = f2b(o[c][r] * l_[r]);
    }
  }
}

extern "C" void kernel_launch(void* const* d_in, const int* in_sizes, int n_in,
                              void* d_out, int out_size, void* d_ws, size_t ws_size,
                              hipStream_t stream) {
  const float* x      = (const float*)d_in[0];
  const float* Wq     = (const float*)d_in[1];
  const float* bq     = (const float*)d_in[2];
  const float* Wk     = (const float*)d_in[3];
  const float* bk     = (const float*)d_in[4];
  const float* Wv     = (const float*)d_in[5];
  const float* bv     = (const float*)d_in[6];
  const float* Wo     = (const float*)d_in[7];
  const float* bo     = (const float*)d_in[8];
  const float* relpos = (const float*)d_in[9];
  const float* gamma  = (const float*)d_in[10];
  const float* beta   = (const float*)d_in[11];
  const float* Wrk    = (const float*)d_in[12];
  const float* brk    = (const float*)d_in[13];
  const float* Wrq    = (const float*)d_in[14];
  const float* brq    = (const float*)d_in[15];
  float* out = (float*)d_out;

  unsigned short* wsu = (unsigned short*)d_ws;
  size_t off = 0;
  auto alloc = [&](size_t n) { unsigned short* p = wsu + off; off += n; return p; };
  unsigned short* xb   = alloc(4194304);
  unsigned short* Eb   = alloc(524288);
  unsigned short* WtQ  = alloc(1048576);
  unsigned short* WtK  = alloc(1048576);
  unsigned short* WtV  = alloc(1048576);
  unsigned short* WtO  = alloc(1048576);
  unsigned short* WtRK = alloc(1048576);
  unsigned short* WtRQ = alloc(1048576);
  unsigned short* Qb2  = alloc(4194304);
  unsigned short* Kb2  = alloc(4194304);
  unsigned short* Vb2  = alloc(4194304);
  unsigned short* ATTb = alloc(4194304);
  unsigned short* RKb2 = alloc(524288);
  unsigned short* RQb2 = alloc(524288);
  float* qrk0 = (float*)(wsu + off); off += 131072;
  float* krq0 = (float*)(wsu + off); off += 131072;

  ln_kernel<<<512, 256, 0, stream>>>(relpos, gamma, beta, Eb);
  conv_bf16<<<2048, 256, 0, stream>>>(x, xb, 4194304);
  dim3 gT(32, 32);
  transp_w<<<gT, 256, 0, stream>>>(Wq, WtQ);
  transp_w<<<gT, 256, 0, stream>>>(Wk, WtK);
  transp_w<<<gT, 256, 0, stream>>>(Wv, WtV);
  transp_w<<<gT, 256, 0, stream>>>(Wo, WtO);
  transp_w<<<gT, 256, 0, stream>>>(Wrk, WtRK);
  transp_w<<<gT, 256, 0, stream>>>(Wrq, WtRQ);

  dim3 gBig(8, 32);
  gemm_bf16<false><<<gBig, 256, 0, stream>>>(xb, WtQ, bq, Qb2);
  gemm_bf16<false><<<gBig, 256, 0, stream>>>(xb, WtK, bk, Kb2);
  gemm_bf16<false><<<gBig, 256, 0, stream>>>(xb, WtV, bv, Vb2);
  dim3 gRel(8, 4);
  gemm_bf16<false><<<gRel, 256, 0, stream>>>(Eb, WtRK, brk, RKb2);
  gemm_bf16<false><<<gRel, 256, 0, stream>>>(Eb, WtRQ, brq, RQb2);

  biasqk<<<1024, 256, 0, stream>>>(Qb2, Kb2, RKb2, RQb2, qrk0, krq0);

  dim3 gAtt(32, NH, NB);
  attn_mfma<<<gAtt, 256, 0, stream>>>(Qb2, Kb2, Vb2, RKb2, RQb2, qrk0, krq0, ATTb);

  gemm_bf16<true><<<gBig, 256, 0, stream>>>(ATTb, WtO, bo, out);
}

// Round 5
// 394.637 us; speedup vs baseline: 6.4493x; 1.0599x over previous
//
#include <hip/hip_runtime.h>
#include <math.h>

#define NH 16
#define HD 64
#define HID 1024
#define SEQ 2048
#define NB 2

typedef __attribute__((ext_vector_type(8))) short short8;
typedef __attribute__((ext_vector_type(4))) float f32x4;
typedef unsigned short u16;
typedef unsigned int u32;

constexpr float LN_EPS_C = 1e-5f;
constexpr float SM_SCALE = 0.07216878364870323f; // 1/sqrt(64*3)

__device__ inline u16 f2b(float f) {
  unsigned u = __builtin_bit_cast(unsigned, f);
  u = (u + 0x7FFFu + ((u >> 16) & 1u)) >> 16;
  return (u16)u;
}
__device__ inline float b2f(u16 h) {
  unsigned u = ((unsigned)h) << 16;
  return __builtin_bit_cast(float, u);
}
__device__ inline u32 pk2(float lo, float hi) {
  return (u32)f2b(lo) | ((u32)f2b(hi) << 16);
}
__device__ inline f32x4 mfma16(short8 a, short8 b, f32x4 c) {
  return __builtin_amdgcn_mfma_f32_16x16x32_bf16(a, b, c, 0, 0, 0);
}
// swizzled read of a [rows][64] bf16 tile whose writes used slot = chunk^(row&7)
__device__ inline short8 swz8(const u16* base, int row, int hc) {
  return *reinterpret_cast<const short8*>(&base[row * 64 + 8 * (hc ^ (row & 7))]);
}

// ---------------- LayerNorm over relpos_table rows -> bf16 ----------------
__global__ __launch_bounds__(256) void ln_kernel(const float* __restrict__ tbl,
    const float* __restrict__ gamma, const float* __restrict__ beta,
    u16* __restrict__ e) {
  int row = blockIdx.x;
  int t = threadIdx.x;
  const float4* rp = reinterpret_cast<const float4*>(tbl + (size_t)row * HID);
  float4 x = rp[t];
  float s = x.x + x.y + x.z + x.w;
  float ss = x.x * x.x + x.y * x.y + x.z * x.z + x.w * x.w;
  #pragma unroll
  for (int o = 1; o < 64; o <<= 1) {
    s += __shfl_xor(s, o);
    ss += __shfl_xor(ss, o);
  }
  __shared__ float sb[4], ssb[4];
  int w = t >> 6;
  if ((t & 63) == 0) { sb[w] = s; ssb[w] = ss; }
  __syncthreads();
  s = sb[0] + sb[1] + sb[2] + sb[3];
  ss = ssb[0] + ssb[1] + ssb[2] + ssb[3];
  float mu = s * (1.0f / HID);
  float var = ss * (1.0f / HID) - mu * mu;
  float rs = rsqrtf(var + LN_EPS_C);
  float4 g = reinterpret_cast<const float4*>(gamma)[t];
  float4 bt = reinterpret_cast<const float4*>(beta)[t];
  ushort4 o4;
  o4.x = f2b((x.x - mu) * rs * g.x + bt.x);
  o4.y = f2b((x.y - mu) * rs * g.y + bt.y);
  o4.z = f2b((x.z - mu) * rs * g.z + bt.z);
  o4.w = f2b((x.w - mu) * rs * g.w + bt.w);
  *reinterpret_cast<ushort4*>(&e[(size_t)row * HID + t * 4]) = o4;
}

// ---------------- f32 -> bf16 convert ----------------
__global__ __launch_bounds__(256) void conv_bf16(const float* __restrict__ src,
    u16* __restrict__ dst, int n) {
  int i = (blockIdx.x * 256 + threadIdx.x) * 8;
  if (i >= n) return;
  float4 a = *reinterpret_cast<const float4*>(&src[i]);
  float4 c = *reinterpret_cast<const float4*>(&src[i + 4]);
  short8 o;
  o[0] = (short)f2b(a.x); o[1] = (short)f2b(a.y); o[2] = (short)f2b(a.z); o[3] = (short)f2b(a.w);
  o[4] = (short)f2b(c.x); o[5] = (short)f2b(c.y); o[6] = (short)f2b(c.z); o[7] = (short)f2b(c.w);
  *reinterpret_cast<short8*>(&dst[i]) = o;
}

// ---------------- W[k][n] f32 -> Wt[n][k] bf16 (transpose+convert) ----------------
__global__ __launch_bounds__(256) void transp_w(const float* __restrict__ W,
    u16* __restrict__ Wt) {
  __shared__ float T[32][33];
  int bn = blockIdx.x * 32, bk = blockIdx.y * 32;
  int t = threadIdx.x;
  int r = t >> 3, c4 = (t & 7) * 4;
  float4 v = *reinterpret_cast<const float4*>(&W[(size_t)(bk + r) * HID + bn + c4]);
  T[r][c4 + 0] = v.x; T[r][c4 + 1] = v.y; T[r][c4 + 2] = v.z; T[r][c4 + 3] = v.w;
  __syncthreads();
  int n = t >> 3, k4 = (t & 7) * 4;
  ushort4 o;
  o.x = f2b(T[k4 + 0][n]); o.y = f2b(T[k4 + 1][n]);
  o.z = f2b(T[k4 + 2][n]); o.w = f2b(T[k4 + 3][n]);
  *reinterpret_cast<ushort4*>(&Wt[(size_t)(bn + n) * HID + bk + k4]) = o;
}

// ---------------- bf16 MFMA GEMM (round-2-proven version) ----------------
template <bool F32OUT>
__global__ __launch_bounds__(256) void gemm_bf16(const u16* __restrict__ A,
    const u16* __restrict__ Bt, const float* __restrict__ bias,
    void* __restrict__ Cout) {
  __shared__ u16 Al[128 * 40];
  __shared__ u16 Bl[128 * 40];
  int t = threadIdx.x;
  int cb = blockIdx.x * 128, rb = blockIdx.y * 128;
  int wv = t >> 6, lane = t & 63, l15 = lane & 15, lg = lane >> 4;
  int wr = (wv >> 1) * 64, wc = (wv & 1) * 64;
  f32x4 acc[4][4];
  #pragma unroll
  for (int i = 0; i < 4; ++i)
    #pragma unroll
    for (int j = 0; j < 4; ++j) acc[i][j] = (f32x4){0.f, 0.f, 0.f, 0.f};
  int sr = t >> 1, sc = (t & 1) * 8;
  const u16* Ap = A + (size_t)(rb + sr) * HID;
  const u16* Bp = Bt + (size_t)(cb + sr) * HID;
  for (int kk = 0; kk < HID; kk += 32) {
    __syncthreads();
    *reinterpret_cast<short8*>(&Al[sr * 40 + sc]) = *reinterpret_cast<const short8*>(&Ap[kk + sc]);
    *reinterpret_cast<short8*>(&Al[sr * 40 + sc + 16]) = *reinterpret_cast<const short8*>(&Ap[kk + sc + 16]);
    *reinterpret_cast<short8*>(&Bl[sr * 40 + sc]) = *reinterpret_cast<const short8*>(&Bp[kk + sc]);
    *reinterpret_cast<short8*>(&Bl[sr * 40 + sc + 16]) = *reinterpret_cast<const short8*>(&Bp[kk + sc + 16]);
    __syncthreads();
    short8 am[4], bn[4];
    #pragma unroll
    for (int i = 0; i < 4; ++i)
      am[i] = *reinterpret_cast<const short8*>(&Al[(wr + i * 16 + l15) * 40 + lg * 8]);
    #pragma unroll
    for (int j = 0; j < 4; ++j)
      bn[j] = *reinterpret_cast<const short8*>(&Bl[(wc + j * 16 + l15) * 40 + lg * 8]);
    #pragma unroll
    for (int i = 0; i < 4; ++i)
      #pragma unroll
      for (int j = 0; j < 4; ++j)
        acc[i][j] = mfma16(am[i], bn[j], acc[i][j]);
  }
  #pragma unroll
  for (int j = 0; j < 4; ++j) {
    float bv = bias[cb + wc + j * 16 + l15];
    #pragma unroll
    for (int i = 0; i < 4; ++i) {
      #pragma unroll
      for (int r = 0; r < 4; ++r) {
        size_t idx = (size_t)(rb + wr + i * 16 + lg * 4 + r) * HID + cb + wc + j * 16 + l15;
        float v = acc[i][j][r] + bv;
        if (F32OUT) reinterpret_cast<float*>(Cout)[idx] = v;
        else reinterpret_cast<u16*>(Cout)[idx] = f2b(v);
      }
    }
  }
}

// ---------------- rank-1 bias precompute: qrk0 = Q.rk[0], krq0 = K.rq[0] ----------------
__global__ __launch_bounds__(256) void biasqk(const u16* __restrict__ Qb,
    const u16* __restrict__ Kb, const u16* __restrict__ RKb,
    const u16* __restrict__ RQb, float* __restrict__ qrk0,
    float* __restrict__ krq0) {
  int o = blockIdx.x * 64 + (threadIdx.x >> 2);
  int sub = threadIdx.x & 3;
  int b = o >> 15, h = (o >> 11) & 15, i = o & 2047;
  size_t rbase = (size_t)(b * SEQ + i) * HID + h * HD + sub * 16;
  size_t tbase = (size_t)h * HD + sub * 16;
  float s1 = 0.f, s2 = 0.f;
  #pragma unroll
  for (int c = 0; c < 2; ++c) {
    short8 qv = *reinterpret_cast<const short8*>(&Qb[rbase + c * 8]);
    short8 rv = *reinterpret_cast<const short8*>(&RKb[tbase + c * 8]);
    short8 kv = *reinterpret_cast<const short8*>(&Kb[rbase + c * 8]);
    short8 uv = *reinterpret_cast<const short8*>(&RQb[tbase + c * 8]);
    #pragma unroll
    for (int j = 0; j < 8; ++j) {
      s1 += b2f((u16)qv[j]) * b2f((u16)rv[j]);
      s2 += b2f((u16)kv[j]) * b2f((u16)uv[j]);
    }
  }
  s1 += __shfl_xor(s1, 1); s1 += __shfl_xor(s1, 2);
  s2 += __shfl_xor(s2, 1); s2 += __shfl_xor(s2, 2);
  if (sub == 0) { qrk0[o] = s1; krq0[o] = s2; }
}

// ---------------- fused DeBERTa attention, MFMA flash, 64x64 tiles ----------------
// LDS (u16 units): Ks [64][64] swz @0; Vt [64 d][72 k] @4096; U @8704 (16896):
//   band stage: RKB [128][64] swz @UO, RQB @UO+8192
//   G phase:    G1T [64][132] @UO (q x w), G2T [64][132] @UO+8448 (k x w)
//   P phase:    Ps [64][72] @UO (q x k, wave-local rows)
__global__ __launch_bounds__(256, 3) void attn_mfma(
    const u16* __restrict__ Qb, const u16* __restrict__ Kb,
    const u16* __restrict__ Vb, const u16* __restrict__ RKb,
    const u16* __restrict__ RQb, const float* __restrict__ qrk0,
    const float* __restrict__ krq0, u16* __restrict__ ATT) {
  __shared__ u16 smem[25600]; // 51200 B -> 3 blocks/CU
  const int KsO = 0, VtO = 4096, UO = 8704;
  const int RKO = UO, RQO = UO + 8192;
  const int G1O = UO, G2O = UO + 8448;
  const int PsO = UO;

  int qt = (int)gridDim.x - 1 - (int)blockIdx.x; // heavy tiles first
  int h = blockIdx.y, b = blockIdx.z;
  int q0 = qt * 64;
  int t = threadIdx.x;
  int wv = t >> 6, lane = t & 63, l15 = lane & 15, lg = lane >> 4;
  int qs = q0 + wv * 16;
  int hoff = h * HD;
  int bh = (b * NH + h) * SEQ;

  size_t qgrow = (size_t)(b * SEQ + qs + l15) * HID + hoff;
  short8 aq0 = *reinterpret_cast<const short8*>(&Qb[qgrow + lg * 8]);
  short8 aq1 = *reinterpret_cast<const short8*>(&Qb[qgrow + 32 + lg * 8]);
  float qb0[4];
  #pragma unroll
  for (int r = 0; r < 4; ++r) qb0[r] = qrk0[bh + qs + lg * 4 + r];

  float m_[4], l_[4];
  f32x4 o[4];
  #pragma unroll
  for (int r = 0; r < 4; ++r) { m_[r] = -INFINITY; l_[r] = 0.f; }
  #pragma unroll
  for (int c = 0; c < 4; ++c) o[c] = (f32x4){0.f, 0.f, 0.f, 0.f};

  const f32x4 Z = (f32x4){0.f, 0.f, 0.f, 0.f};
  int vr = t >> 2, vc8 = (t & 3) * 8; // K/V staging mapping

  for (int kt = 0; kt <= qt; ++kt) {
    int k0 = kt * 64;
    int dt = qt - kt;
    bool banded = (dt <= 8);
    int wlo = 448 - 64 * dt; if (wlo < 0) wlo = 0;
    __syncthreads(); // #1: previous iteration fully consumed
    // ---- stage K (write-side XOR swizzle, stride 64) ----
    {
      const u16* kg = &Kb[(size_t)(b * SEQ + k0 + vr) * HID + hoff];
      int c0 = vc8 >> 3;
      *reinterpret_cast<short8*>(&smem[KsO + vr * 64 + 8 * (c0 ^ (vr & 7))]) =
          *reinterpret_cast<const short8*>(&kg[vc8]);
      *reinterpret_cast<short8*>(&smem[KsO + vr * 64 + 8 * ((c0 + 4) ^ (vr & 7))]) =
          *reinterpret_cast<const short8*>(&kg[vc8 + 32]);
      // ---- stage V transposed (scalar, proven) ----
      const u16* vg = &Vb[(size_t)(b * SEQ + k0 + vr) * HID + hoff];
      short8 v0 = *reinterpret_cast<const short8*>(&vg[vc8]);
      short8 v1 = *reinterpret_cast<const short8*>(&vg[vc8 + 32]);
      #pragma unroll
      for (int j = 0; j < 8; ++j) smem[VtO + (vc8 + j) * 72 + vr] = (u16)v0[j];
      #pragma unroll
      for (int j = 0; j < 8; ++j) smem[VtO + (vc8 + 32 + j) * 72 + vr] = (u16)v1[j];
    }
    if (banded) {
      for (int e2 = t; e2 < 1024; e2 += 256) {
        int rr = e2 >> 3, cch = e2 & 7;
        int wr2 = wlo + rr; if (wr2 > 511) wr2 = 511;
        size_t gb = (size_t)wr2 * HID + hoff + cch * 8;
        int slot = 8 * (cch ^ (rr & 7));
        *reinterpret_cast<short8*>(&smem[RKO + rr * 64 + slot]) =
            *reinterpret_cast<const short8*>(&RKb[gb]);
        *reinterpret_cast<short8*>(&smem[RQO + rr * 64 + slot]) =
            *reinterpret_cast<const short8*>(&RQb[gb]);
      }
    }
    float kq[4];
    if (!banded) {
      #pragma unroll
      for (int c = 0; c < 4; ++c) kq[c] = krq0[bh + k0 + c * 16 + l15];
    }
    __syncthreads(); // #2: staging visible everywhere

    // ---- c2c logits ----
    f32x4 s[4];
    #pragma unroll
    for (int c = 0; c < 4; ++c) {
      short8 kb0 = swz8(&smem[KsO], c * 16 + l15, lg);
      short8 kb1 = swz8(&smem[KsO], c * 16 + l15, 4 + lg);
      s[c] = mfma16(aq1, kb1, mfma16(aq0, kb0, Z));
    }

    if (banded) {
      // ---- G1T = RK_band . Q^T ; G2T = RQ_band . K^T (bf16-packed in regs) ----
      u32 g1p[16], g2p[16];
      #pragma unroll
      for (int cw = 0; cw < 8; ++cw) {
        short8 r0 = swz8(&smem[RKO], cw * 16 + l15, lg);
        short8 r1 = swz8(&smem[RKO], cw * 16 + l15, 4 + lg);
        f32x4 g = mfma16(r1, aq1, mfma16(r0, aq0, Z));
        g1p[2 * cw] = pk2(g[0], g[1]);
        g1p[2 * cw + 1] = pk2(g[2], g[3]);
      }
      short8 kw0 = swz8(&smem[KsO], wv * 16 + l15, lg);
      short8 kw1 = swz8(&smem[KsO], wv * 16 + l15, 4 + lg);
      #pragma unroll
      for (int cw = 0; cw < 8; ++cw) {
        short8 u0 = swz8(&smem[RQO], cw * 16 + l15, lg);
        short8 u1 = swz8(&smem[RQO], cw * 16 + l15, 4 + lg);
        f32x4 g = mfma16(u1, kw1, mfma16(u0, kw0, Z));
        g2p[2 * cw] = pk2(g[0], g[1]);
        g2p[2 * cw + 1] = pk2(g[2], g[3]);
      }
      __syncthreads(); // #3: all band reads done; U can be overwritten
      #pragma unroll
      for (int cw = 0; cw < 8; ++cw) {
        *reinterpret_cast<uint2*>(&smem[G1O + (wv * 16 + l15) * 132 + cw * 16 + lg * 4]) =
            make_uint2(g1p[2 * cw], g1p[2 * cw + 1]);
        *reinterpret_cast<uint2*>(&smem[G2O + (wv * 16 + l15) * 132 + cw * 16 + lg * 4]) =
            make_uint2(g2p[2 * cw], g2p[2 * cw + 1]);
      }
      __syncthreads(); // #4: G visible to all waves
      #pragma unroll
      for (int c = 0; c < 4; ++c) {
        #pragma unroll
        for (int r = 0; r < 4; ++r) {
          int q = qs + lg * 4 + r;
          int k = k0 + c * 16 + l15;
          int wi = 511 - (q - k) - wlo; if (wi < 0) wi = 0;
          s[c][r] += b2f(smem[G1O + (wv * 16 + lg * 4 + r) * 132 + wi]) +
                     b2f(smem[G2O + (c * 16 + l15) * 132 + wi]);
        }
      }
      __syncthreads(); // #5: gathers done; U free for Ps
    } else {
      #pragma unroll
      for (int c = 0; c < 4; ++c)
        #pragma unroll
        for (int r = 0; r < 4; ++r) s[c][r] += qb0[r] + kq[c];
    }

    // ---- scale + causal mask ----
    #pragma unroll
    for (int c = 0; c < 4; ++c) {
      #pragma unroll
      for (int r = 0; r < 4; ++r) {
        float v = s[c][r] * SM_SCALE;
        if (dt == 0) {
          int ql = wv * 16 + lg * 4 + r, kl = c * 16 + l15;
          if (ql < kl) v = -INFINITY;
        }
        s[c][r] = v;
      }
    }
    // ---- online softmax (shfl_xor reductions, proven) ----
    float alpha[4];
    #pragma unroll
    for (int r = 0; r < 4; ++r) {
      float mx = fmaxf(fmaxf(s[0][r], s[1][r]), fmaxf(s[2][r], s[3][r]));
      mx = fmaxf(mx, __shfl_xor(mx, 1));
      mx = fmaxf(mx, __shfl_xor(mx, 2));
      mx = fmaxf(mx, __shfl_xor(mx, 4));
      mx = fmaxf(mx, __shfl_xor(mx, 8));
      float mn = fmaxf(m_[r], mx);
      alpha[r] = __expf(m_[r] - mn);
      float ps = 0.f;
      #pragma unroll
      for (int c = 0; c < 4; ++c) {
        float p = __expf(s[c][r] - mn);
        s[c][r] = p;
        ps += p;
      }
      ps += __shfl_xor(ps, 1);
      ps += __shfl_xor(ps, 2);
      ps += __shfl_xor(ps, 4);
      ps += __shfl_xor(ps, 8);
      l_[r] = l_[r] * alpha[r] + ps;
      m_[r] = mn;
    }
    // ---- P -> Ps (wave-local rows), rescale O ----
    #pragma unroll
    for (int c = 0; c < 4; ++c) {
      #pragma unroll
      for (int r = 0; r < 4; ++r) {
        smem[PsO + (wv * 16 + lg * 4 + r) * 72 + c * 16 + l15] = f2b(s[c][r]);
        o[c][r] *= alpha[r];
      }
    }
    short8 ap0 = *reinterpret_cast<const short8*>(&smem[PsO + (wv * 16 + l15) * 72 + lg * 8]);
    short8 ap1 = *reinterpret_cast<const short8*>(&smem[PsO + (wv * 16 + l15) * 72 + 32 + lg * 8]);
    #pragma unroll
    for (int c = 0; c < 4; ++c) {
      short8 vb0 = *reinterpret_cast<const short8*>(&smem[VtO + (c * 16 + l15) * 72 + lg * 8]);
      short8 vb1 = *reinterpret_cast<const short8*>(&smem[VtO + (c * 16 + l15) * 72 + 32 + lg * 8]);
      o[c] = mfma16(ap1, vb1, mfma16(ap0, vb0, o[c]));
    }
  }
  #pragma unroll
  for (int r = 0; r < 4; ++r) l_[r] = 1.0f / l_[r];
  #pragma unroll
  for (int c = 0; c < 4; ++c) {
    #pragma unroll
    for (int r = 0; r < 4; ++r) {
      size_t ob = (size_t)(b * SEQ + qs + lg * 4 + r) * HID + hoff + c * 16 + l15;
      ATT[ob] = f2b(o[c][r] * l_[r]);
    }
  }
}

extern "C" void kernel_launch(void* const* d_in, const int* in_sizes, int n_in,
                              void* d_out, int out_size, void* d_ws, size_t ws_size,
                              hipStream_t stream) {
  const float* x      = (const float*)d_in[0];
  const float* Wq     = (const float*)d_in[1];
  const float* bq     = (const float*)d_in[2];
  const float* Wk     = (const float*)d_in[3];
  const float* bk     = (const float*)d_in[4];
  const float* Wv     = (const float*)d_in[5];
  const float* bv     = (const float*)d_in[6];
  const float* Wo     = (const float*)d_in[7];
  const float* bo     = (const float*)d_in[8];
  const float* relpos = (const float*)d_in[9];
  const float* gamma  = (const float*)d_in[10];
  const float* beta   = (const float*)d_in[11];
  const float* Wrk    = (const float*)d_in[12];
  const float* brk    = (const float*)d_in[13];
  const float* Wrq    = (const float*)d_in[14];
  const float* brq    = (const float*)d_in[15];
  float* out = (float*)d_out;

  u16* wsu = (u16*)d_ws;
  size_t off = 0;
  auto alloc = [&](size_t n) { u16* p = wsu + off; off += n; return p; };
  u16* xb   = alloc(4194304);
  u16* Eb   = alloc(524288);
  u16* WtQ  = alloc(1048576);
  u16* WtK  = alloc(1048576);
  u16* WtV  = alloc(1048576);
  u16* WtO  = alloc(1048576);
  u16* WtRK = alloc(1048576);
  u16* WtRQ = alloc(1048576);
  u16* Qb2  = alloc(4194304);
  u16* Kb2  = alloc(4194304);
  u16* Vb2  = alloc(4194304);
  u16* ATTb = alloc(4194304);
  u16* RKb2 = alloc(524288);
  u16* RQb2 = alloc(524288);
  float* qrk0 = (float*)(wsu + off); off += 131072;
  float* krq0 = (float*)(wsu + off); off += 131072;

  ln_kernel<<<512, 256, 0, stream>>>(relpos, gamma, beta, Eb);
  conv_bf16<<<2048, 256, 0, stream>>>(x, xb, 4194304);
  dim3 gT(32, 32);
  transp_w<<<gT, 256, 0, stream>>>(Wq, WtQ);
  transp_w<<<gT, 256, 0, stream>>>(Wk, WtK);
  transp_w<<<gT, 256, 0, stream>>>(Wv, WtV);
  transp_w<<<gT, 256, 0, stream>>>(Wo, WtO);
  transp_w<<<gT, 256, 0, stream>>>(Wrk, WtRK);
  transp_w<<<gT, 256, 0, stream>>>(Wrq, WtRQ);

  dim3 gBig(8, 32);
  gemm_bf16<false><<<gBig, 256, 0, stream>>>(xb, WtQ, bq, Qb2);
  gemm_bf16<false><<<gBig, 256, 0, stream>>>(xb, WtK, bk, Kb2);
  gemm_bf16<false><<<gBig, 256, 0, stream>>>(xb, WtV, bv, Vb2);
  dim3 gRel(8, 4);
  gemm_bf16<false><<<gRel, 256, 0, stream>>>(Eb, WtRK, brk, RKb2);
  gemm_bf16<false><<<gRel, 256, 0, stream>>>(Eb, WtRQ, brq, RQb2);

  biasqk<<<1024, 256, 0, stream>>>(Qb2, Kb2, RKb2, RQb2, qrk0, krq0);

  dim3 gAtt(32, NH, NB);
  attn_mfma<<<gAtt, 256, 0, stream>>>(Qb2, Kb2, Vb2, RKb2, RQb2, qrk0, krq0, ATTb);

  gemm_bf16<true><<<gBig, 256, 0, stream>>>(ATTb, WtO, bo, out);
}